// Round 1
// 172.491 us; speedup vs baseline: 1.0592x; 1.0592x over previous
//
#include <hip/hip_runtime.h>
#include <cstdint>
#include <cstddef>

// Problem constants (fixed by the reference file)
#define B_SZ  8
#define C_IN  2049          // N_FFT/2+1
#define T_FR  345           // MAX_FRAMES
#define NFFT  4096
#define HOPSZ 1024
#define MFR   2760          // B_SZ*T_FR frames
#define NPAIR 173           // ceil(345/2) frame-pairs per batch
#define TW    1.5339807878856412e-3f   // 2*pi/4096
#define TW256 2.4543692606170259e-2f   // 2*pi/256

// e^{i*pi/8} family for the in-register 16-pt IDFT
#define C8P   0.70710678118654752f
#define C16C  0.92387953251128676f
#define C16S  0.38268343236508977f

__device__ __forceinline__ unsigned short f2b(float f) {
  union { float f; unsigned int u; } v; v.f = f;
  unsigned int r = v.u + 0x7fffu + ((v.u >> 16) & 1u);  // RNE to bf16
  return (unsigned short)(r >> 16);
}
__device__ __forceinline__ float b2f(unsigned int h) {
  union { unsigned int u; float f; } v; v.u = h << 16;
  return v.f;
}

// ---------------------------------------------------------------------------
// trans: [B, C_IN, T_FR] re/im fp32 -> spec[(b*T+t)*2049 + c] packed bf16 pair
// (re low 16, im high 16). LDS 64x64 tile transpose; fast-math recombine:
// r' = x*sqrt(r^2+i^2)*rsqrt(x^2+i^2), x = r+eps  (bf16 target, approx ok).
__global__ void trans(const float* __restrict__ re, const float* __restrict__ im,
                      unsigned int* __restrict__ spec) {
  __shared__ float tr[64][65];
  __shared__ float ti[64][65];
  const int tid = threadIdx.x;
  const int t0 = blockIdx.x * 64;
  const int c0 = blockIdx.y * 64;
  const int b  = blockIdx.z;
#pragma unroll
  for (int pass = 0; pass < 16; ++pass) {
    int idx = pass * 256 + tid;
    int tt = idx & 63, cc = idx >> 6;
    int c = c0 + cc, t = t0 + tt;
    float rp = 0.f, ip = 0.f;
    if (c < C_IN && t < T_FR) {
      size_t off = ((size_t)b * C_IN + c) * T_FR + t;
      float r = re[off], i = im[off];
      float x  = r + 1.1920929e-7f;            // real + eps (phase arg)
      float r2 = r * r + i * i;
      float h2 = fmaxf(x * x + i * i, 1e-35f);
      float inv = __builtin_amdgcn_sqrtf(r2) * __builtin_amdgcn_rsqf(h2);
      rp = x * inv;                             // mag*cos(phase)
      ip = i * inv;                             // mag*sin(phase)
    }
    tr[cc][tt] = rp;
    ti[cc][tt] = ip;
  }
  __syncthreads();
#pragma unroll
  for (int pass = 0; pass < 16; ++pass) {
    int idx = pass * 256 + tid;
    int kk = idx & 63, tt = idx >> 6;
    int c = c0 + kk, t = t0 + tt;
    if (c < C_IN && t < T_FR) {
      size_t mrow = (size_t)b * T_FR + t;
      unsigned int pk = ((unsigned int)f2b(ti[kk][tt]) << 16) | f2b(tr[kk][tt]);
      spec[mrow * C_IN + c] = pk;
    }
  }
}

// ---------------------------------------------------------------------------
// In-register 16-point inverse DFT: y[m] = sum_a z[a] e^{+2pi i a m/16}.
// 4x4 decomposition (a = a0 + 4*a1, m = m0 + 4*m1), hardwired twiddles.
__device__ __forceinline__ void cmul(float& xr, float& xi, float cr, float ci) {
  float t = xr * cr - xi * ci;
  xi = xr * ci + xi * cr;
  xr = t;
}

__device__ __forceinline__ void idft16(float* zr, float* zi) {
  float vr[16], vi[16];
  // layer 1: radix-4 over a1 on (a0, a0+4, a0+8, a0+12) -> v[a0*4 + m0]
#pragma unroll
  for (int a0 = 0; a0 < 4; ++a0) {
    float z0r = zr[a0],      z0i = zi[a0];
    float z1r = zr[a0 + 4],  z1i = zi[a0 + 4];
    float z2r = zr[a0 + 8],  z2i = zi[a0 + 8];
    float z3r = zr[a0 + 12], z3i = zi[a0 + 12];
    float t0r = z0r + z2r, t0i = z0i + z2i;
    float t1r = z0r - z2r, t1i = z0i - z2i;
    float t2r = z1r + z3r, t2i = z1i + z3i;
    float t3r = z3i - z1i, t3i = z1r - z3r;   // +i*(z1 - z3)
    vr[a0 * 4 + 0] = t0r + t2r; vi[a0 * 4 + 0] = t0i + t2i;
    vr[a0 * 4 + 1] = t1r + t3r; vi[a0 * 4 + 1] = t1i + t3i;
    vr[a0 * 4 + 2] = t0r - t2r; vi[a0 * 4 + 2] = t0i - t2i;
    vr[a0 * 4 + 3] = t1r - t3r; vi[a0 * 4 + 3] = t1i - t3i;
  }
  // twiddles v[a0,m0] *= e^{2pi i a0 m0/16}  (t = a0*m0)
  cmul(vr[5],  vi[5],  C16C, C16S);            // t=1
  cmul(vr[6],  vi[6],  C8P,  C8P);             // t=2
  cmul(vr[7],  vi[7],  C16S, C16C);            // t=3
  cmul(vr[9],  vi[9],  C8P,  C8P);             // t=2
  { float t = vr[10]; vr[10] = -vi[10]; vi[10] = t; }  // t=4 -> *i
  cmul(vr[11], vi[11], -C8P, C8P);             // t=6
  cmul(vr[13], vi[13], C16S, C16C);            // t=3
  cmul(vr[14], vi[14], -C8P, C8P);             // t=6
  cmul(vr[15], vi[15], -C16C, -C16S);          // t=9
  // layer 2: radix-4 over a0 for each m0 -> out[m0 + 4*m1]
#pragma unroll
  for (int m0 = 0; m0 < 4; ++m0) {
    float z0r = vr[0 + m0],  z0i = vi[0 + m0];
    float z1r = vr[4 + m0],  z1i = vi[4 + m0];
    float z2r = vr[8 + m0],  z2i = vi[8 + m0];
    float z3r = vr[12 + m0], z3i = vi[12 + m0];
    float t0r = z0r + z2r, t0i = z0i + z2i;
    float t1r = z0r - z2r, t1i = z0i - z2i;
    float t2r = z1r + z3r, t2i = z1i + z3i;
    float t3r = z3i - z1i, t3i = z1r - z3r;   // +i*(z1 - z3)
    zr[m0 + 0]  = t0r + t2r; zi[m0 + 0]  = t0i + t2i;
    zr[m0 + 4]  = t1r + t3r; zi[m0 + 4]  = t1i + t3i;
    zr[m0 + 8]  = t0r - t2r; zi[m0 + 8]  = t0i - t2i;
    zr[m0 + 12] = t1r - t3r; zi[m0 + 12] = t1i - t3i;
  }
}

// Chained twiddle: z[q] *= cis(q*step), q=1..15 (recurrence off one sincos).
__device__ __forceinline__ void twiddle_chain(float* zr, float* zi, float step) {
  float sA, cA; __sincosf(step, &sA, &cA);
  float cr = cA, ci = sA;
  cmul(zr[1], zi[1], cr, ci);
#pragma unroll
  for (int q = 2; q < 16; ++q) {
    float nr = cr * cA - ci * sA;
    ci = cr * sA + ci * cA;
    cr = nr;
    cmul(zr[q], zi[q], cr, ci);
  }
}

// ---------------------------------------------------------------------------
// Real-pair IFFT, radix-16^3 register formulation.
// One 4096-pt complex IFFT yields TWO real frames (a = Re, b = Im).
// Hermitian combine done in the initial register load (mirror read, L1-hot):
//   k in [1,2047]: Z[k] = (ar - bi) + i(ai + br); Z[4096-k] = (ar + bi) + i(br - ai)
//   Z[0] = ar0 + i*br0,  Z[2048] = arN + i*brN
// Decomposition: k = k0 + 16 k1 + 256 k2, n = n0 + 16 n1 + 256 n2.
//   stage1 (thread k0+16k1, regs over k2): A[k0,k1;n0] = IDFT16_k2
//   stage2 (thread k0+16n0): *cis(2pi n0 k1/256), IDFT16_k1 -> B[k0;n0,n1]
//   stage3 (thread n0+16n1): *cis(2pi (n0+16n1) k0/4096), IDFT16_k0 -> X[256n2+tid]
// LDS: two 17-float-padded [16x16x16] exchange buffers (34 KiB), 3 barriers.
__global__ __launch_bounds__(256, 4) void ifft_frames(const unsigned int* __restrict__ spec,
                                                      unsigned short* __restrict__ Fr) {
  __shared__ float LR[4352];   // 17*16*16
  __shared__ float LI[4352];
  const int tid = threadIdx.x;
  const int j = blockIdx.x, b = blockIdx.y;
  const int ta = b * T_FR + 2 * j;            // frame a (always valid)
  const bool hasb = (2 * j + 1) < T_FR;       // frame b exists (t=344 leftover)
  const unsigned int* spa = spec + (size_t)ta * C_IN;
  const unsigned int* spb = spa + C_IN;

  float zr[16], zi[16];
  // ---- load + hermitian combine: z[q] = Z[tid + 256*q]
#pragma unroll
  for (int q = 0; q < 16; ++q) {
    int n = tid + 256 * q;
    int k = (n <= 2048) ? n : (4096 - n);
    unsigned int va = spa[k];
    unsigned int vb = hasb ? spb[k] : 0u;
    float ar = b2f(va & 0xffffu), ai = b2f(va >> 16);
    float br = b2f(vb & 0xffffu), bi = b2f(vb >> 16);
    bool dc  = (n == 0) | (n == 2048);        // DC/Nyquist: drop imag parts
    bool mir = n > 2048;
    float zzr = mir ? (ar + bi) : (ar - bi);
    float zzi = mir ? (br - ai) : (ai + br);
    zr[q] = dc ? ar : zzr;
    zi[q] = dc ? br : zzi;
  }
  // ---- stage 1: IDFT16 over k2 (no twiddle); write A[k0,k1,n0]
  idft16(zr, zi);
  {
    int base = (tid >> 4) + 17 * (tid & 15);   // k1 + 17*k0
#pragma unroll
    for (int m = 0; m < 16; ++m) { LR[base + 272 * m] = zr[m]; LI[base + 272 * m] = zi[m]; }
  }
  __syncthreads();
  // ---- stage 2: thread (k0=tid&15, n0=tid>>4); read A over k1 (contiguous)
  {
    int base = 17 * (tid & 15) + 272 * (tid >> 4);
#pragma unroll
    for (int q = 0; q < 16; ++q) { zr[q] = LR[base + q]; zi[q] = LI[base + q]; }
  }
  __syncthreads();
  twiddle_chain(zr, zi, (float)(tid >> 4) * TW256);   // cis(2pi n0 k1/256)
  idft16(zr, zi);
  {
    int base = (tid & 15) + 17 * (tid >> 4);   // k0 + 17*n0
#pragma unroll
    for (int m = 0; m < 16; ++m) { LR[base + 272 * m] = zr[m]; LI[base + 272 * m] = zi[m]; }
  }
  __syncthreads();
  // ---- stage 3: thread (n0=tid&15, n1=tid>>4); read B over k0 (contiguous)
  {
    int base = 17 * (tid & 15) + 272 * (tid >> 4);
#pragma unroll
    for (int q = 0; q < 16; ++q) { zr[q] = LR[base + q]; zi[q] = LI[base + q]; }
  }
  twiddle_chain(zr, zi, (float)tid * TW);      // cis(2pi (n0+16n1) k0/4096), n0+16n1 == tid
  idft16(zr, zi);
  // ---- windowed bf16 pack + store: sample n = 256*m + tid; a = Re, b = Im.
  // Pair packing via shfl with lane^1: even lanes store frame a dwords,
  // odd lanes store frame b dwords (win/256 folded into the store).
  unsigned int* da = (unsigned int*)(Fr + (size_t)ta * NFFT);
  unsigned int* db = (unsigned int*)(Fr + (size_t)(ta + 1) * NFFT);
  const bool even = (tid & 1) == 0;
#pragma unroll
  for (int m = 0; m < 16; ++m) {
    int n = 256 * m + tid;
    float w = (0.5f - 0.5f * __cosf((float)n * TW)) * 0.00390625f;   // win/256
    float va = zr[m] * w, vb = zi[m] * w;
    float xa = __shfl_xor(va, 1);
    float xb = __shfl_xor(vb, 1);
    unsigned int pa = ((unsigned int)f2b(xa) << 16) | f2b(va);  // even: (n, n+1)
    unsigned int pb = ((unsigned int)f2b(vb) << 16) | f2b(xb);  // odd:  (n-1, n)
    int dw = 128 * m + (tid >> 1);
    if (even)      da[dw] = pa;
    else if (hasb) db[dw] = pb;
  }
}

// ---------------------------------------------------------------------------
// Overlap-add gather, x4 vectorized. Quads are 4-aligned and boundaries are at
// multiples of 1024, so all 4 outputs of a quad share the same tap range ->
// one ushort4 load per tap, float4 wsi load, float4 store.
__global__ void ola(const unsigned short* __restrict__ Fr, const float* __restrict__ wsi,
                    float* __restrict__ out, int length) {
  int q = blockIdx.x * 256 + threadIdx.x;
  int b = blockIdx.y;
  int p4 = q * 4;
  if (p4 >= length) return;
  int s0 = (NFFT / 2) + p4;
  int tlo = (s0 - 3072) >> 10;
  tlo = tlo < 0 ? 0 : tlo;
  int thi = s0 >> 10;
  thi = thi > (T_FR - 1) ? (T_FR - 1) : thi;
  float a0 = 0.f, a1 = 0.f, a2 = 0.f, a3 = 0.f;
  for (int t = tlo; t <= thi; ++t) {
    const unsigned short* fp = Fr + ((size_t)(b * T_FR + t)) * NFFT + (s0 - (t << 10));
    ushort4 v = *(const ushort4*)fp;          // 8B aligned: s0 % 4 == 0
    a0 += b2f(v.x); a1 += b2f(v.y); a2 += b2f(v.z); a3 += b2f(v.w);
  }
  float4 wv = *(const float4*)(wsi + s0);
  float4 o; o.x = a0 * wv.x; o.y = a1 * wv.y; o.z = a2 * wv.z; o.w = a3 * wv.w;
  *(float4*)(out + (size_t)b * length + p4) = o;
}

// ---------------------------------------------------------------------------
extern "C" void kernel_launch(void* const* d_in, const int* in_sizes, int n_in,
                              void* d_out, int out_size, void* d_ws, size_t ws_size,
                              hipStream_t stream) {
  const float* re  = (const float*)d_in[0];
  const float* im  = (const float*)d_in[1];
  // d_in[2] (inverse_basis) unused — spectral identity HW-verified previously.
  const float* wsi = (const float*)d_in[3];
  float* out = (float*)d_out;
  const int length = out_size / B_SZ;   // 352800

  // Workspace (45.2 MB): spec packed-bf16 [MFR x 2049], Fr bf16 [MFR x 4096].
  unsigned int*   spec = (unsigned int*)d_ws;
  unsigned short* Fr   = (unsigned short*)(spec + (size_t)MFR * C_IN);

  trans<<<dim3((T_FR + 63) / 64, (C_IN + 63) / 64, B_SZ), 256, 0, stream>>>(re, im, spec);
  ifft_frames<<<dim3(NPAIR, B_SZ), 256, 0, stream>>>(spec, Fr);
  ola<<<dim3((length / 4 + 255) / 256, B_SZ), 256, 0, stream>>>(Fr, wsi, out, length);
}